// Round 13
// baseline (1235.711 us; speedup 1.0000x reference)
//
#include <hip/hip_runtime.h>
#include <stdint.h>

typedef __bf16 bf16;
typedef __bf16 bf16x8 __attribute__((ext_vector_type(8)));
typedef __bf16 bf16x4 __attribute__((ext_vector_type(4)));
typedef float f32x4 __attribute__((ext_vector_type(4)));

#define WIN 8

__device__ __forceinline__ float sigm(float x) { return 1.0f / (1.0f + __expf(-x)); }
__device__ __forceinline__ float tanhfast(float x) { return 2.0f / (1.0f + __expf(-2.0f * x)) - 1.0f; }

__device__ __forceinline__ void gload16(const void* g, void* l) {
    __builtin_amdgcn_global_load_lds((const __attribute__((address_space(1))) void*)g,
                                     (__attribute__((address_space(3))) void*)l, 16, 0, 0);
}

struct StepArgs {
    const bf16* A1;      // GEMM A source (X0 for MODE0, h_prev for MODE1, x-slot for MODE2)
    const bf16* A2;      // MODE2 h_prev (K 1024..1535)
    const bf16* W;       // B^T operand (weights; row = output col)
    const float* bias;
    const bf16* P0;      // MODE1: P0 [4096][2048] input projections
    float* Cst;          // cell state [4096,512] f32
    bf16* Hout;          // output h
    float* Hf32;         // optional f32 copy of h
    const bf16* Hprev;   // h_prev for masked carry
    int l;               // window slot (for mask)
    int firstStep;
};

// 256(M)x128(N) tile, BK=32, 4 waves (2M x 2N; wave tile 128x64), double-buffered
// 48KB LDS -> 2 blocks/CU: two independent barrier domains per CU so one block's
// MFMA fills the other's stage/barrier stalls (R12 lesson: intra-block pipelining
// is null at 1 block/CU). Per-block schedule = R9-proven discipline: 2 phases/K-tile
// (m-halves), reads pre-barrier, lgkmcnt(0)+sched_barrier+setprio around MFMA,
// staging smeared 3 loads/phase, vmcnt(0) only at tile boundary.
// LDS rows are 64B -> bank access is 2-way-free WITHOUT swizzle (linear staging).
// MODE 0: plain GEMM (P0 = X0 @ W^T), natural cols, output stride 2048
// MODE 1: layer-0 LSTM step: acc = h@whh^T (K=512), epilogue adds P0 gather + bias
// MODE 2: layer-1 LSTM step: acc = [x,h]@[wih|whh]^T (K=1536), epilogue adds bias
template<int MODE>
__global__ __launch_bounds__(256, 2)
void step_pair(StepArgs fa, StepArgs ba) {
    const StepArgs a = blockIdx.z ? ba : fa;
    __shared__ alignas(16) char lds[49152];   // 2 x (A 16KB + B 8KB)

    constexpr int SA1 = (MODE == 0) ? 512 : 1024;   // A row stride
    constexpr int SW  = (MODE == 2) ? 1536 : 512;   // B-operand row stride
    constexpr int SH  = (MODE == 0) ? 2048 : (MODE == 1 ? 1024 : 512);
    constexpr int SHP = (MODE == 1) ? 1024 : 512;   // Hprev stride

    const int tid = threadIdx.x;
    const int w = tid >> 6;            // 0..3
    const int lane = tid & 63;
    const int wm = w >> 1, wn = w & 1; // wave tile: rows wm*128, cols wn*64
    const int bx = blockIdx.x, by = blockIdx.y;
    const int rowBase = bx * 256;

    int KB;
    if (MODE == 0) KB = 16;
    else if (MODE == 1) KB = a.firstStep ? 0 : 16;
    else KB = a.firstStep ? 32 : 48;

    // ---- staging addresses (linear; LDS dest = uniform base + lane*16) ----
    const int lr = lane >> 2;          // row within 16-row chunk
    const int lcB = (lane & 3) * 8;    // source col offset (elements, 16B)

    // A: 256 rows; wave w stages rows w*64 + j*16 + lr, j=0..3
    const bf16* aP[4];
    const bf16* a2P[4];
#pragma unroll
    for (int j = 0; j < 4; ++j) {
        const int r = w * 64 + j * 16 + lr;
        const int n = rowBase + r;
        aP[j] = a.A1 ? (a.A1 + (size_t)n * SA1 + lcB) : (const bf16*)0;
        if (MODE == 2) a2P[j] = a.A2 ? (a.A2 + (size_t)n * 512 + lcB) : (const bf16*)0;
    }
    // B: 128 rows; wave w stages rows w*32 + j*16 + lr, j=0..1
    const bf16* bP[2];
#pragma unroll
    for (int j = 0; j < 2; ++j) {
        const int r = w * 32 + j * 16 + lr;
        int wr;
        if (MODE == 0) wr = by * 128 + r;
        else wr = ((r >> 4) & 3) * 512 + by * 32 + (r >> 6) * 16 + (r & 15);
        bP[j] = a.W + (size_t)wr * SW + lcB;
    }

    // ---- compute-side fragment offsets (64B rows; no swizzle needed) ----
    const int l15 = lane & 15, l4 = lane >> 4;
    const int aOffB = (wm * 128 + l15) * 64 + l4 * 16;   // + m*16*64
    const int bOffB = (wn * 64 + l15) * 64 + l4 * 16;    // + n*16*64

    f32x4 acc[8][4];
    const f32x4 zf = {0.f, 0.f, 0.f, 0.f};
#pragma unroll
    for (int m = 0; m < 8; ++m)
#pragma unroll
        for (int n = 0; n < 4; ++n) acc[m][n] = zf;

    auto STAGE_A = [&](char* Sd, int kt, int j) {
        const int ke = kt * 32;
        const bf16* src;
        if (MODE == 2) src = (kt < 32) ? (aP[j] + ke) : (a2P[j] + (ke - 1024));
        else src = aP[j] + ke;
        gload16(src, Sd + (w * 64 + j * 16) * 64);
    };
    auto STAGE_B = [&](char* Sd, int kt, int j) {
        gload16(bP[j] + kt * 32, Sd + 16384 + (w * 32 + j * 16) * 64);
    };

    if (KB > 0) {
        // prologue: stage tile 0, drain, barrier
#pragma unroll
        for (int j = 0; j < 4; ++j) STAGE_A(lds, 0, j);
#pragma unroll
        for (int j = 0; j < 2; ++j) STAGE_B(lds, 0, j);
        asm volatile("s_waitcnt vmcnt(0)" ::: "memory");
        __builtin_amdgcn_s_barrier();

        for (int t = 0; t < KB; ++t) {
            const int cur = t & 1;
            const char* Ab = lds + cur * 24576;
            const char* Bb = Ab + 16384;
            char* Sd = lds + (cur ^ 1) * 24576;
            const bool pf = (t + 1 < KB);
            bf16x8 af[4], bv[4];

            // ---- phase 1: m-half 0; stage A0,A1,B0 of t+1 ----
            if (pf) { STAGE_A(Sd, t + 1, 0); STAGE_A(Sd, t + 1, 1); STAGE_B(Sd, t + 1, 0); }
#pragma unroll
            for (int i = 0; i < 4; ++i)
                af[i] = *(const bf16x8*)(Ab + aOffB + i * 1024);
#pragma unroll
            for (int n = 0; n < 4; ++n)
                bv[n] = *(const bf16x8*)(Bb + bOffB + n * 1024);
            __builtin_amdgcn_s_barrier();
            asm volatile("s_waitcnt lgkmcnt(0)" ::: "memory");
            __builtin_amdgcn_sched_barrier(0);
            __builtin_amdgcn_s_setprio(1);
#pragma unroll
            for (int i = 0; i < 4; ++i)
#pragma unroll
                for (int n = 0; n < 4; ++n)
                    acc[i][n] = __builtin_amdgcn_mfma_f32_16x16x32_bf16(af[i], bv[n], acc[i][n], 0, 0, 0);
            __builtin_amdgcn_s_setprio(0);
            __builtin_amdgcn_sched_barrier(0);
            __builtin_amdgcn_s_barrier();

            // ---- phase 2: m-half 1 (B reused in regs); stage A2,A3,B1 of t+1 ----
            if (pf) { STAGE_A(Sd, t + 1, 2); STAGE_A(Sd, t + 1, 3); STAGE_B(Sd, t + 1, 1); }
#pragma unroll
            for (int i = 0; i < 4; ++i)
                af[i] = *(const bf16x8*)(Ab + aOffB + (4 + i) * 1024);
            __builtin_amdgcn_s_barrier();
            asm volatile("s_waitcnt lgkmcnt(0)" ::: "memory");
            __builtin_amdgcn_sched_barrier(0);
            __builtin_amdgcn_s_setprio(1);
#pragma unroll
            for (int i = 0; i < 4; ++i)
#pragma unroll
                for (int n = 0; n < 4; ++n)
                    acc[4 + i][n] = __builtin_amdgcn_mfma_f32_16x16x32_bf16(af[i], bv[n], acc[4 + i][n], 0, 0, 0);
            __builtin_amdgcn_s_setprio(0);
            __builtin_amdgcn_sched_barrier(0);
            if (pf) asm volatile("s_waitcnt vmcnt(0)" ::: "memory");
            __builtin_amdgcn_s_barrier();
        }
    }

    if (MODE == 0) {
#pragma unroll
        for (int m = 0; m < 8; ++m)
#pragma unroll
            for (int n = 0; n < 4; ++n) {
                const int col = by * 128 + wn * 64 + n * 16 + l15;
#pragma unroll
                for (int e = 0; e < 4; ++e) {
                    const int row = rowBase + wm * 128 + m * 16 + l4 * 4 + e;
                    a.Hout[(size_t)row * SH + col] = (bf16)acc[m][n][e];
                }
            }
        return;
    }

    // ---- LSTM epilogue: n-frag index = gate (i,f,g,o), unit = by*32 + wn*16 + l15 ----
    const int u = by * 32 + wn * 16 + l15;
    const float bi = a.bias[u];
    const float bff = a.bias[512 + u];
    const float bg = a.bias[1024 + u];
    const float bo = a.bias[1536 + u];
#pragma unroll
    for (int m = 0; m < 8; ++m) {
#pragma unroll
        for (int e = 0; e < 4; ++e) {
            const int n = rowBase + wm * 128 + m * 16 + l4 * 4 + e;
            const int s = n >> 3;
            const int p = s + a.l - WIN;
            const bool valid = ((unsigned)p < 512u);
            float gi = acc[m][0][e] + bi;
            float gf = acc[m][1][e] + bff;
            float gg = acc[m][2][e] + bg;
            float go = acc[m][3][e] + bo;
            if (MODE == 1) {
                const int pc = p < 0 ? 0 : (p > 511 ? 511 : p);
                const size_t pr = (size_t)(pc * 8 + (n & 7)) * 2048;
                gi += (float)a.P0[pr + u];
                gf += (float)a.P0[pr + 512 + u];
                gg += (float)a.P0[pr + 1024 + u];
                go += (float)a.P0[pr + 1536 + u];
            }
            const float cold = a.firstStep ? 0.0f : a.Cst[(size_t)n * 512 + u];
            const float cnew = sigm(gf) * cold + sigm(gi) * tanhfast(gg);
            const float hnew = sigm(go) * tanhfast(cnew);
            float hv, cv;
            if (valid) { hv = hnew; cv = cnew; }
            else {
                hv = a.Hprev ? (float)a.Hprev[(size_t)n * SHP + u] : 0.0f;
                cv = cold;
            }
            a.Cst[(size_t)n * 512 + u] = cv;
            a.Hout[(size_t)n * SH + u] = (bf16)hv;
            if (a.Hf32) a.Hf32[(size_t)n * 512 + u] = hv;
        }
    }
}

__global__ void embed_kernel(const int* __restrict__ tok, const float* __restrict__ tbl,
                             bf16* __restrict__ X0) {
    const int n = blockIdx.x;
    const int t = tok[n];
    const float4 v = ((const float4*)(tbl + (size_t)t * 512))[threadIdx.x];
    bf16x4 o = {(bf16)v.x, (bf16)v.y, (bf16)v.z, (bf16)v.w};
    ((bf16x4*)(X0 + (size_t)n * 512))[threadIdx.x] = o;
}

// Fused weight prep: y=0..3 -> cvt 2048x512 (wih0f, wih0b, whh0f, whh0b);
// y=4..5 -> build w1 [2048][1536] = [wih1 | whh1].
__global__ void prep_kernel(const float* __restrict__ wih0f, const float* __restrict__ wih0b,
                            const float* __restrict__ whh0f, const float* __restrict__ whh0b,
                            const float* __restrict__ wih1f, const float* __restrict__ whh1f,
                            const float* __restrict__ wih1b, const float* __restrict__ whh1b,
                            bf16* __restrict__ d0, bf16* __restrict__ d1,
                            bf16* __restrict__ d2, bf16* __restrict__ d3,
                            bf16* __restrict__ d4, bf16* __restrict__ d5) {
    const int r = blockIdx.x;
    const int y = blockIdx.y;
    if (y < 4) {
        const float* s = (y == 0) ? wih0f : (y == 1) ? wih0b : (y == 2) ? whh0f : whh0b;
        bf16* d = (y == 0) ? d0 : (y == 1) ? d1 : (y == 2) ? d2 : d3;
        const int k = threadIdx.x * 2;
        const float2 v = *(const float2*)(s + (size_t)r * 512 + k);
        d[(size_t)r * 512 + k] = (bf16)v.x;
        d[(size_t)r * 512 + k + 1] = (bf16)v.y;
    } else {
        const float* wih = (y == 4) ? wih1f : wih1b;
        const float* whh = (y == 4) ? whh1f : whh1b;
        bf16* d = (y == 4) ? d4 : d5;
        for (int k = threadIdx.x; k < 1536; k += 256) {
            const float v = (k < 1024) ? wih[(size_t)r * 1024 + k] : whh[(size_t)r * 512 + (k - 1024)];
            d[(size_t)r * 1536 + k] = (bf16)v;
        }
    }
}

__global__ void combine_kernel(const float* __restrict__ hf, const float* __restrict__ hb,
                               float* __restrict__ out) {
    const int i = blockIdx.x * 256 + threadIdx.x;
    const float4 x = ((const float4*)hf)[i];
    const float4 y = ((const float4*)hb)[i];
    float4 r;
    r.x = (x.x + y.x) * 0.5f;
    r.y = (x.y + y.y) * 0.5f;
    r.z = (x.z + y.z) * 0.5f;
    r.w = (x.w + y.w) * 0.5f;
    ((float4*)out)[i] = r;
}

extern "C" void kernel_launch(void* const* d_in, const int* in_sizes, int n_in,
                              void* d_out, int out_size, void* d_ws, size_t ws_size,
                              hipStream_t stream) {
    (void)in_sizes; (void)n_in; (void)out_size;
    const int*   tok   = (const int*)d_in[0];
    const float* tbl   = (const float*)d_in[1];
    const float* wih0f = (const float*)d_in[2];
    const float* whh0f = (const float*)d_in[3];
    const float* b0f   = (const float*)d_in[4];
    const float* wih0b = (const float*)d_in[5];
    const float* whh0b = (const float*)d_in[6];
    const float* b0b   = (const float*)d_in[7];
    const float* wih1f = (const float*)d_in[8];
    const float* whh1f = (const float*)d_in[9];
    const float* b1f   = (const float*)d_in[10];
    const float* wih1b = (const float*)d_in[11];
    const float* whh1b = (const float*)d_in[12];
    const float* b1b   = (const float*)d_in[13];

    char* ws = (char*)d_ws;
    size_t off = 0;
    auto alloc = [&](size_t bytes) -> char* {
        char* p = ws + off;
        off += (bytes + 255) & ~(size_t)255;
        return p;
    };
    bf16* wih0f_b = (bf16*)alloc((size_t)2048 * 512 * 2);
    bf16* wih0b_b = (bf16*)alloc((size_t)2048 * 512 * 2);
    bf16* whh0f_b = (bf16*)alloc((size_t)2048 * 512 * 2);
    bf16* whh0b_b = (bf16*)alloc((size_t)2048 * 512 * 2);
    bf16* w1f_b   = (bf16*)alloc((size_t)2048 * 1536 * 2);
    bf16* w1b_b   = (bf16*)alloc((size_t)2048 * 1536 * 2);
    bf16* X0      = (bf16*)alloc((size_t)4096 * 512 * 2);
    bf16* P0f     = (bf16*)alloc((size_t)4096 * 2048 * 2);
    bf16* P0b     = (bf16*)alloc((size_t)4096 * 2048 * 2);
    bf16* X1      = (bf16*)alloc((size_t)17 * 4096 * 1024 * 2);
    float* c0f    = (float*)alloc((size_t)4096 * 512 * 4);
    float* c0b    = (float*)alloc((size_t)4096 * 512 * 4);
    bf16* h1f0    = (bf16*)alloc((size_t)4096 * 512 * 2);
    bf16* h1f1    = (bf16*)alloc((size_t)4096 * 512 * 2);
    bf16* h1b0    = (bf16*)alloc((size_t)4096 * 512 * 2);
    bf16* h1b1    = (bf16*)alloc((size_t)4096 * 512 * 2);
    float* hf32f  = (float*)alloc((size_t)4096 * 512 * 4);
    float* hf32b  = (float*)alloc((size_t)4096 * 512 * 4);
    if (off > ws_size) return;  // workspace too small; fail cleanly

    bf16* h1f[2] = {h1f0, h1f1};
    bf16* h1b[2] = {h1b0, h1b1};

    prep_kernel<<<dim3(2048, 6), 256, 0, stream>>>(wih0f, wih0b, whh0f, whh0b,
                                                   wih1f, whh1f, wih1b, whh1b,
                                                   wih0f_b, wih0b_b, whh0f_b, whh0b_b,
                                                   w1f_b, w1b_b);
    embed_kernel<<<4096, 128, 0, stream>>>(tok, tbl, X0);

    dim3 g(16, 16, 2), blk(256, 1, 1);

    // P0 = X0 @ wih0^T for both directions  -> [4096 token][2048 gate-unit]
    {
        StepArgs f{}, b{};
        f.A1 = X0; f.W = wih0f_b; f.Hout = P0f;
        b = f; b.W = wih0b_b; b.Hout = P0b;
        step_pair<0><<<g, blk, 0, stream>>>(f, b);
    }

    const size_t SLOT = (size_t)4096 * 1024;

    // layer 0: fwd l=0..16 paired with bwd l=16..0
    for (int i = 0; i <= 16; ++i) {
        const int lf = i, lb = 16 - i;
        StepArgs f{}, b{};
        f.A1 = (lf == 0) ? (const bf16*)0 : X1 + (size_t)(lf - 1) * SLOT;
        f.W = whh0f_b; f.bias = b0f; f.P0 = P0f; f.Cst = c0f;
        f.Hout = X1 + (size_t)lf * SLOT; f.Hprev = f.A1;
        f.l = lf; f.firstStep = (lf == 0) ? 1 : 0;
        b.A1 = (lb == 16) ? (const bf16*)0 : X1 + (size_t)(lb + 1) * SLOT + 512;
        b.W = whh0b_b; b.bias = b0b; b.P0 = P0b; b.Cst = c0b;
        b.Hout = X1 + (size_t)lb * SLOT + 512; b.Hprev = b.A1;
        b.l = lb; b.firstStep = (lb == 16) ? 1 : 0;
        step_pair<1><<<g, blk, 0, stream>>>(f, b);
    }

    // layer 1: only steps needed for the center slot: fwd l=0..8, bwd l=16..8
    for (int i = 0; i <= 8; ++i) {
        const int lf = i, lb = 16 - i;
        StepArgs f{}, b{};
        f.A1 = X1 + (size_t)lf * SLOT;
        f.A2 = (i == 0) ? (const bf16*)0 : h1f[(i + 1) & 1];
        f.W = w1f_b; f.bias = b1f; f.Cst = c0f;  // c0f reused as layer-1 fwd cell state
        f.Hout = h1f[i & 1]; f.Hf32 = (i == 8) ? hf32f : (float*)0;
        f.Hprev = f.A2;
        f.l = lf; f.firstStep = (i == 0) ? 1 : 0;
        b.A1 = X1 + (size_t)lb * SLOT;
        b.A2 = (i == 0) ? (const bf16*)0 : h1b[(i + 1) & 1];
        b.W = w1b_b; b.bias = b1b; b.Cst = c0b;
        b.Hout = h1b[i & 1]; b.Hf32 = (i == 8) ? hf32b : (float*)0;
        b.Hprev = b.A2;
        b.l = lb; b.firstStep = (i == 0) ? 1 : 0;
        step_pair<2><<<g, blk, 0, stream>>>(f, b);
    }

    combine_kernel<<<2048, 256, 0, stream>>>(hf32f, hf32b, (float*)d_out);
}

// Round 14
// 1064.097 us; speedup vs baseline: 1.1613x; 1.1613x over previous
//
#include <hip/hip_runtime.h>
#include <stdint.h>

typedef __bf16 bf16;
typedef __bf16 bf16x8 __attribute__((ext_vector_type(8)));
typedef __bf16 bf16x4 __attribute__((ext_vector_type(4)));
typedef float f32x4 __attribute__((ext_vector_type(4)));

#define WIN 8

__device__ __forceinline__ float sigm(float x) { return 1.0f / (1.0f + __expf(-x)); }
__device__ __forceinline__ float tanhfast(float x) { return 2.0f / (1.0f + __expf(-2.0f * x)) - 1.0f; }

__device__ __forceinline__ void gload16(const void* g, void* l) {
    __builtin_amdgcn_global_load_lds((const __attribute__((address_space(1))) void*)g,
                                     (__attribute__((address_space(3))) void*)l, 16, 0, 0);
}

struct StepArgs {
    const bf16* A1;      // GEMM A source (X0 for MODE0, h_prev for MODE1, x-slot for MODE2)
    const bf16* A2;      // MODE2 h_prev (K 1024..1535)
    const bf16* W;       // B^T operand (weights; row = output col)
    const float* bias;
    const bf16* P0;      // MODE1: P0 [4096][2048], col = u*4 + gate (gate-interleaved)
    float* Cst;          // cell state [4096,512] f32
    bf16* Hout;          // output h
    float* Hf32;         // optional f32 copy of h
    const bf16* Hprev;   // h_prev for masked carry
    int l;               // window slot (for mask)
    int firstStep;
};

// 256x256 tile, 8 waves (2M x 4N, wave tile 128x64), BK=64, double-buffered LDS.
// R9-proven 4-quadrant-phase K-loop (champion schedule; 5 pipelining variants were
// null-or-worse). MODE0's B rows are permuted so P0's column c holds gate-unit
// (g=c&3, u=c>>2) -> MODE1's epilogue gather becomes 32 coalesced bf16x4 loads
// (4 gates per 8B load; 16 lanes = 128B contiguous) instead of 128 scalar loads.
// MODE 0: plain GEMM (P0 = X0 @ W^T), gate-interleaved cols, output stride 2048
// MODE 1: layer-0 LSTM step: acc = h@whh^T (K=512), epilogue adds P0 gather + bias
// MODE 2: layer-1 LSTM step: acc = [x,h]@[wih|whh]^T (K=1536), epilogue adds bias
template<int MODE>
__global__ __launch_bounds__(512, 2)
void step_pair(StepArgs fa, StepArgs ba) {
    const StepArgs a = blockIdx.z ? ba : fa;
    __shared__ alignas(16) char lds[131072];   // 2 x (A 32KB + B 32KB)

    constexpr int SA1 = (MODE == 0) ? 512 : 1024;   // A row stride
    constexpr int SW  = (MODE == 2) ? 1536 : 512;   // B-operand row stride
    constexpr int SH  = (MODE == 0) ? 2048 : (MODE == 1 ? 1024 : 512);
    constexpr int SHP = (MODE == 1) ? 1024 : 512;   // Hprev stride

    const int tid = threadIdx.x;
    const int w = tid >> 6;
    const int lane = tid & 63;
    const int wm = w >> 2, wn = w & 3;
    const int bx = blockIdx.x, by = blockIdx.y;
    const int rowBase = bx * 256;

    int KB;
    if (MODE == 0) KB = 8;
    else if (MODE == 1) KB = a.firstStep ? 0 : 8;
    else KB = a.firstStep ? 16 : 24;

    // ---- staging addresses (pre-swizzled global source -> linear LDS) ----
    const int lq = lane >> 3;          // row within 8-row chunk
    const int lc = lane & 7;           // 16B chunk within 128B row
    const int swz = 8 * (lc ^ lq);     // source column pre-swizzle (elements)

    const bf16* aP[4];
    const bf16* a2P[4];
    const bf16* bP[4];
#pragma unroll
    for (int q = 0; q < 4; ++q) {
        const int r = w * 32 + q * 8 + lq;      // tile row 0..255
        const int n = rowBase + r;
        aP[q] = a.A1 ? (a.A1 + (size_t)n * SA1 + swz) : (const bf16*)0;
        if (MODE == 2) a2P[q] = a.A2 ? (a.A2 + (size_t)n * 512 + swz) : (const bf16*)0;
        int wr;
        if (MODE == 0) wr = (r & 3) * 512 + by * 64 + (r >> 2);   // gate-interleave cols
        else wr = ((r & 63) >> 4) * 512 + by * 64 + (r >> 6) * 16 + (r & 15);
        bP[q] = a.W + (size_t)wr * SW + swz;
    }

    // ---- compute-side fragment offsets ----
    const int l15 = lane & 15, l4 = lane >> 4;
    const int key = (l15 & 7) << 4;                      // XOR swizzle key (row & 7)<<4
    const int aBase = (wm * 128 + l15) * 128;            // + m*2048
    const int bBase = (wn * 64 + l15) * 128;             // + n*2048

    f32x4 acc[8][4];
    const f32x4 zf = {0.f, 0.f, 0.f, 0.f};
#pragma unroll
    for (int m = 0; m < 8; ++m)
#pragma unroll
        for (int n = 0; n < 4; ++n) acc[m][n] = zf;

    auto CHUNK = [&](char* Sd, int kb, int q) {
        const int ke = kb * 64;
        const int ldsOff = (w * 32 + q * 8) * 128;
        const bf16* srcA;
        if (MODE == 2) srcA = (kb < 16) ? (aP[q] + ke) : (a2P[q] + (ke - 1024));
        else srcA = aP[q] + ke;
        gload16(srcA, Sd + ldsOff);
        gload16(bP[q] + ke, Sd + 32768 + ldsOff);
    };

    if (KB > 0) {
        // prologue: stage tile 0 fully, drain, barrier
#pragma unroll
        for (int q = 0; q < 4; ++q) CHUNK(lds, 0, q);
        asm volatile("s_waitcnt vmcnt(0)" ::: "memory");
        __builtin_amdgcn_s_barrier();

        for (int t = 0; t < KB; ++t) {
            const int cur = t & 1;
            const char* Ab = lds + cur * 65536;
            const char* Bb = Ab + 32768;
            char* Sd = lds + (cur ^ 1) * 65536;
            const bool pf = (t + 1 < KB);
            const int ko0 = (l4 * 16) ^ key;
            const int ko1 = (64 + l4 * 16) ^ key;
            bf16x8 af0[4], af1[4], bv0[4], bv1[4];

            // ---- phase 1: (mh0, kk0), stage chunks 0,1 ----
            if (pf) { CHUNK(Sd, t + 1, 0); CHUNK(Sd, t + 1, 1); }
#pragma unroll
            for (int i = 0; i < 4; ++i)
                af0[i] = *(const bf16x8*)(Ab + aBase + i * 2048 + ko0);
#pragma unroll
            for (int n = 0; n < 4; ++n)
                bv0[n] = *(const bf16x8*)(Bb + bBase + n * 2048 + ko0);
            __builtin_amdgcn_s_barrier();
            asm volatile("s_waitcnt lgkmcnt(0)" ::: "memory");
            __builtin_amdgcn_sched_barrier(0);
            __builtin_amdgcn_s_setprio(1);
#pragma unroll
            for (int i = 0; i < 4; ++i)
#pragma unroll
                for (int n = 0; n < 4; ++n)
                    acc[i][n] = __builtin_amdgcn_mfma_f32_16x16x32_bf16(af0[i], bv0[n], acc[i][n], 0, 0, 0);
            __builtin_amdgcn_s_setprio(0);
            __builtin_amdgcn_sched_barrier(0);
            __builtin_amdgcn_s_barrier();

            // ---- phase 2: (mh1, kk0), stage chunk 2 ----
            if (pf) CHUNK(Sd, t + 1, 2);
#pragma unroll
            for (int i = 0; i < 4; ++i)
                af1[i] = *(const bf16x8*)(Ab + aBase + (4 + i) * 2048 + ko0);
            __builtin_amdgcn_s_barrier();
            asm volatile("s_waitcnt lgkmcnt(0)" ::: "memory");
            __builtin_amdgcn_sched_barrier(0);
            __builtin_amdgcn_s_setprio(1);
#pragma unroll
            for (int i = 0; i < 4; ++i)
#pragma unroll
                for (int n = 0; n < 4; ++n)
                    acc[4 + i][n] = __builtin_amdgcn_mfma_f32_16x16x32_bf16(af1[i], bv0[n], acc[4 + i][n], 0, 0, 0);
            __builtin_amdgcn_s_setprio(0);
            __builtin_amdgcn_sched_barrier(0);
            __builtin_amdgcn_s_barrier();

            // ---- phase 3: (mh0, kk1), stage chunk 3 ----
            if (pf) CHUNK(Sd, t + 1, 3);
#pragma unroll
            for (int i = 0; i < 4; ++i)
                af0[i] = *(const bf16x8*)(Ab + aBase + i * 2048 + ko1);
#pragma unroll
            for (int n = 0; n < 4; ++n)
                bv1[n] = *(const bf16x8*)(Bb + bBase + n * 2048 + ko1);
            __builtin_amdgcn_s_barrier();
            asm volatile("s_waitcnt lgkmcnt(0)" ::: "memory");
            __builtin_amdgcn_sched_barrier(0);
            __builtin_amdgcn_s_setprio(1);
#pragma unroll
            for (int i = 0; i < 4; ++i)
#pragma unroll
                for (int n = 0; n < 4; ++n)
                    acc[i][n] = __builtin_amdgcn_mfma_f32_16x16x32_bf16(af0[i], bv1[n], acc[i][n], 0, 0, 0);
            __builtin_amdgcn_s_setprio(0);
            __builtin_amdgcn_sched_barrier(0);
            __builtin_amdgcn_s_barrier();

            // ---- phase 4: (mh1, kk1), no staging; vmcnt(0) before closing barrier ----
#pragma unroll
            for (int i = 0; i < 4; ++i)
                af1[i] = *(const bf16x8*)(Ab + aBase + (4 + i) * 2048 + ko1);
            __builtin_amdgcn_s_barrier();
            asm volatile("s_waitcnt lgkmcnt(0)" ::: "memory");
            __builtin_amdgcn_sched_barrier(0);
            __builtin_amdgcn_s_setprio(1);
#pragma unroll
            for (int i = 0; i < 4; ++i)
#pragma unroll
                for (int n = 0; n < 4; ++n)
                    acc[4 + i][n] = __builtin_amdgcn_mfma_f32_16x16x32_bf16(af1[i], bv1[n], acc[4 + i][n], 0, 0, 0);
            __builtin_amdgcn_s_setprio(0);
            __builtin_amdgcn_sched_barrier(0);
            if (pf) asm volatile("s_waitcnt vmcnt(0)" ::: "memory");
            __builtin_amdgcn_s_barrier();
        }
    }

    if (MODE == 0) {
#pragma unroll
        for (int m = 0; m < 8; ++m)
#pragma unroll
            for (int n = 0; n < 4; ++n) {
                const int col = by * 256 + wn * 64 + n * 16 + l15;
#pragma unroll
                for (int e = 0; e < 4; ++e) {
                    const int row = rowBase + wm * 128 + m * 16 + l4 * 4 + e;
                    a.Hout[(size_t)row * SH + col] = (bf16)acc[m][n][e];
                }
            }
        return;
    }

    // ---- LSTM epilogue: n-frag index = gate (i,f,g,o), unit = by*64 + wn*16 + l15 ----
    const int u = by * 64 + wn * 16 + l15;
    const float bi = a.bias[u];
    const float bff = a.bias[512 + u];
    const float bg = a.bias[1024 + u];
    const float bo = a.bias[1536 + u];
#pragma unroll
    for (int m = 0; m < 8; ++m) {
        const int n0 = rowBase + wm * 128 + m * 16 + l4 * 4;
        bf16x4 pg[4];
        if (MODE == 1) {
            const int s0 = n0 >> 3;
            int pc = s0 + a.l - WIN;
            pc = pc < 0 ? 0 : (pc > 511 ? 511 : pc);
            const size_t base = ((size_t)pc * 8 + (n0 & 7)) * 2048 + u * 4;
#pragma unroll
            for (int e = 0; e < 4; ++e)
                pg[e] = *(const bf16x4*)(a.P0 + base + (size_t)e * 2048);
        }
#pragma unroll
        for (int e = 0; e < 4; ++e) {
            const int n = n0 + e;
            const int s = n >> 3;
            const int p = s + a.l - WIN;
            const bool valid = ((unsigned)p < 512u);
            float gi = acc[m][0][e] + bi;
            float gf = acc[m][1][e] + bff;
            float gg = acc[m][2][e] + bg;
            float go = acc[m][3][e] + bo;
            if (MODE == 1) {
                gi += (float)pg[e][0];
                gf += (float)pg[e][1];
                gg += (float)pg[e][2];
                go += (float)pg[e][3];
            }
            const float cold = a.firstStep ? 0.0f : a.Cst[(size_t)n * 512 + u];
            const float cnew = sigm(gf) * cold + sigm(gi) * tanhfast(gg);
            const float hnew = sigm(go) * tanhfast(cnew);
            float hv, cv;
            if (valid) { hv = hnew; cv = cnew; }
            else {
                hv = a.Hprev ? (float)a.Hprev[(size_t)n * SHP + u] : 0.0f;
                cv = cold;
            }
            a.Cst[(size_t)n * 512 + u] = cv;
            a.Hout[(size_t)n * SH + u] = (bf16)hv;
            if (a.Hf32) a.Hf32[(size_t)n * 512 + u] = hv;
        }
    }
}

__global__ void embed_kernel(const int* __restrict__ tok, const float* __restrict__ tbl,
                             bf16* __restrict__ X0) {
    const int n = blockIdx.x;
    const int t = tok[n];
    const float4 v = ((const float4*)(tbl + (size_t)t * 512))[threadIdx.x];
    bf16x4 o = {(bf16)v.x, (bf16)v.y, (bf16)v.z, (bf16)v.w};
    ((bf16x4*)(X0 + (size_t)n * 512))[threadIdx.x] = o;
}

// Fused weight prep: y=0..3 -> cvt 2048x512 (wih0f, wih0b, whh0f, whh0b);
// y=4..5 -> build w1 [2048][1536] = [wih1 | whh1].
__global__ void prep_kernel(const float* __restrict__ wih0f, const float* __restrict__ wih0b,
                            const float* __restrict__ whh0f, const float* __restrict__ whh0b,
                            const float* __restrict__ wih1f, const float* __restrict__ whh1f,
                            const float* __restrict__ wih1b, const float* __restrict__ whh1b,
                            bf16* __restrict__ d0, bf16* __restrict__ d1,
                            bf16* __restrict__ d2, bf16* __restrict__ d3,
                            bf16* __restrict__ d4, bf16* __restrict__ d5) {
    const int r = blockIdx.x;
    const int y = blockIdx.y;
    if (y < 4) {
        const float* s = (y == 0) ? wih0f : (y == 1) ? wih0b : (y == 2) ? whh0f : whh0b;
        bf16* d = (y == 0) ? d0 : (y == 1) ? d1 : (y == 2) ? d2 : d3;
        const int k = threadIdx.x * 2;
        const float2 v = *(const float2*)(s + (size_t)r * 512 + k);
        d[(size_t)r * 512 + k] = (bf16)v.x;
        d[(size_t)r * 512 + k + 1] = (bf16)v.y;
    } else {
        const float* wih = (y == 4) ? wih1f : wih1b;
        const float* whh = (y == 4) ? whh1f : whh1b;
        bf16* d = (y == 4) ? d4 : d5;
        for (int k = threadIdx.x; k < 1536; k += 256) {
            const float v = (k < 1024) ? wih[(size_t)r * 1024 + k] : whh[(size_t)r * 512 + (k - 1024)];
            d[(size_t)r * 1536 + k] = (bf16)v;
        }
    }
}

__global__ void combine_kernel(const float* __restrict__ hf, const float* __restrict__ hb,
                               float* __restrict__ out) {
    const int i = blockIdx.x * 256 + threadIdx.x;
    const float4 x = ((const float4*)hf)[i];
    const float4 y = ((const float4*)hb)[i];
    float4 r;
    r.x = (x.x + y.x) * 0.5f;
    r.y = (x.y + y.y) * 0.5f;
    r.z = (x.z + y.z) * 0.5f;
    r.w = (x.w + y.w) * 0.5f;
    ((float4*)out)[i] = r;
}

extern "C" void kernel_launch(void* const* d_in, const int* in_sizes, int n_in,
                              void* d_out, int out_size, void* d_ws, size_t ws_size,
                              hipStream_t stream) {
    (void)in_sizes; (void)n_in; (void)out_size;
    const int*   tok   = (const int*)d_in[0];
    const float* tbl   = (const float*)d_in[1];
    const float* wih0f = (const float*)d_in[2];
    const float* whh0f = (const float*)d_in[3];
    const float* b0f   = (const float*)d_in[4];
    const float* wih0b = (const float*)d_in[5];
    const float* whh0b = (const float*)d_in[6];
    const float* b0b   = (const float*)d_in[7];
    const float* wih1f = (const float*)d_in[8];
    const float* whh1f = (const float*)d_in[9];
    const float* b1f   = (const float*)d_in[10];
    const float* wih1b = (const float*)d_in[11];
    const float* whh1b = (const float*)d_in[12];
    const float* b1b   = (const float*)d_in[13];

    char* ws = (char*)d_ws;
    size_t off = 0;
    auto alloc = [&](size_t bytes) -> char* {
        char* p = ws + off;
        off += (bytes + 255) & ~(size_t)255;
        return p;
    };
    bf16* wih0f_b = (bf16*)alloc((size_t)2048 * 512 * 2);
    bf16* wih0b_b = (bf16*)alloc((size_t)2048 * 512 * 2);
    bf16* whh0f_b = (bf16*)alloc((size_t)2048 * 512 * 2);
    bf16* whh0b_b = (bf16*)alloc((size_t)2048 * 512 * 2);
    bf16* w1f_b   = (bf16*)alloc((size_t)2048 * 1536 * 2);
    bf16* w1b_b   = (bf16*)alloc((size_t)2048 * 1536 * 2);
    bf16* X0      = (bf16*)alloc((size_t)4096 * 512 * 2);
    bf16* P0f     = (bf16*)alloc((size_t)4096 * 2048 * 2);
    bf16* P0b     = (bf16*)alloc((size_t)4096 * 2048 * 2);
    bf16* X1      = (bf16*)alloc((size_t)17 * 4096 * 1024 * 2);
    float* c0f    = (float*)alloc((size_t)4096 * 512 * 4);
    float* c0b    = (float*)alloc((size_t)4096 * 512 * 4);
    bf16* h1f0    = (bf16*)alloc((size_t)4096 * 512 * 2);
    bf16* h1f1    = (bf16*)alloc((size_t)4096 * 512 * 2);
    bf16* h1b0    = (bf16*)alloc((size_t)4096 * 512 * 2);
    bf16* h1b1    = (bf16*)alloc((size_t)4096 * 512 * 2);
    float* hf32f  = (float*)alloc((size_t)4096 * 512 * 4);
    float* hf32b  = (float*)alloc((size_t)4096 * 512 * 4);
    if (off > ws_size) return;  // workspace too small; fail cleanly

    bf16* h1f[2] = {h1f0, h1f1};
    bf16* h1b[2] = {h1b0, h1b1};

    prep_kernel<<<dim3(2048, 6), 256, 0, stream>>>(wih0f, wih0b, whh0f, whh0b,
                                                   wih1f, whh1f, wih1b, whh1b,
                                                   wih0f_b, wih0b_b, whh0f_b, whh0b_b,
                                                   w1f_b, w1b_b);
    embed_kernel<<<4096, 128, 0, stream>>>(tok, tbl, X0);

    dim3 g(16, 8, 2), blk(512, 1, 1);

    // P0 = X0 @ wih0^T for both directions -> [4096 token][2048], col = u*4+gate
    {
        StepArgs f{}, b{};
        f.A1 = X0; f.W = wih0f_b; f.Hout = P0f;
        b = f; b.W = wih0b_b; b.Hout = P0b;
        step_pair<0><<<g, blk, 0, stream>>>(f, b);
    }

    const size_t SLOT = (size_t)4096 * 1024;

    // layer 0: fwd l=0..16 paired with bwd l=16..0
    for (int i = 0; i <= 16; ++i) {
        const int lf = i, lb = 16 - i;
        StepArgs f{}, b{};
        f.A1 = (lf == 0) ? (const bf16*)0 : X1 + (size_t)(lf - 1) * SLOT;
        f.W = whh0f_b; f.bias = b0f; f.P0 = P0f; f.Cst = c0f;
        f.Hout = X1 + (size_t)lf * SLOT; f.Hprev = f.A1;
        f.l = lf; f.firstStep = (lf == 0) ? 1 : 0;
        b.A1 = (lb == 16) ? (const bf16*)0 : X1 + (size_t)(lb + 1) * SLOT + 512;
        b.W = whh0b_b; b.bias = b0b; b.P0 = P0b; b.Cst = c0b;
        b.Hout = X1 + (size_t)lb * SLOT + 512; b.Hprev = b.A1;
        b.l = lb; b.firstStep = (lb == 16) ? 1 : 0;
        step_pair<1><<<g, blk, 0, stream>>>(f, b);
    }

    // layer 1: only steps needed for the center slot: fwd l=0..8, bwd l=16..8
    for (int i = 0; i <= 8; ++i) {
        const int lf = i, lb = 16 - i;
        StepArgs f{}, b{};
        f.A1 = X1 + (size_t)lf * SLOT;
        f.A2 = (i == 0) ? (const bf16*)0 : h1f[(i + 1) & 1];
        f.W = w1f_b; f.bias = b1f; f.Cst = c0f;  // c0f reused as layer-1 fwd cell state
        f.Hout = h1f[i & 1]; f.Hf32 = (i == 8) ? hf32f : (float*)0;
        f.Hprev = f.A2;
        f.l = lf; f.firstStep = (i == 0) ? 1 : 0;
        b.A1 = X1 + (size_t)lb * SLOT;
        b.A2 = (i == 0) ? (const bf16*)0 : h1b[(i + 1) & 1];
        b.W = w1b_b; b.bias = b1b; b.Cst = c0b;
        b.Hout = h1b[i & 1]; b.Hf32 = (i == 8) ? hf32b : (float*)0;
        b.Hprev = b.A2;
        b.l = lb; b.firstStep = (i == 0) ? 1 : 0;
        step_pair<2><<<g, blk, 0, stream>>>(f, b);
    }

    combine_kernel<<<2048, 256, 0, stream>>>(hf32f, hf32b, (float*)d_out);
}